// Round 1
// 379.175 us; speedup vs baseline: 1.1896x; 1.1896x over previous
//
#include <hip/hip_runtime.h>

// LightGCN: x0 = dropout(concat(user,item)); out = (x0 + A x0 + A^2 x0 + A^3 x0)/4
// R9: fp16 intermediates for the SpMM gather path.
//   rocprof R8: each k_spmm fetches 336MB (vs ~50MB compulsory) because every
//   edge gathers a 256B fp32 x-row that misses the 4MB/XCD L2 (38.4MB working
//   set, random cols). Storing X0/Y1/Y2 as fp16 halves both bytes-per-gather
//   (128B) and the working set (19.2MB -> better L2 hit rate). Accumulation
//   stays fp32 in registers; only storage is fp16 (0.5ulp ~ 4-8e-6 at these
//   magnitudes, A-gain on random errors ~0.5, so no amplification).
// CSR build (R8, unchanged): two-level counting sort
//   k_bin:  edges -> 147 buckets (row>>10), LDS-aggregated dense appends.
//   k_bsort: 1 block/bucket: LDS hist(1024 rows) -> scan -> rp, then scatter
//            into the bucket's dense ev region.
// SpMM: wave=row, 4 edge-groups x 16 lanes; lane holds 4 dims (8B fp16).

static constexpr int NU = 100000;
static constexpr int NI = 50000;
static constexpr int NN = NU + NI;       // 150000
static constexpr int D  = 64;
static constexpr int E  = 2400000;
static constexpr int XN = NN * D;        // 9,600,000
static constexpr int XH = XN / 2;        // 4,800,000
static constexpr int NB = (NN + 1023) >> 10;   // 147 buckets
static constexpr int BPC = 24000;        // bucket staging cap (mean 16327, +59 sigma)
static constexpr int BIN_T = 256;
static constexpr int BIN_U = 16;
static constexpr int BIN_CHUNK = BIN_T * BIN_U;   // 4096

typedef _Float16 half_t;
typedef _Float16 half4 __attribute__((ext_vector_type(4)));

__device__ __forceinline__ unsigned rotl32(unsigned x, int r) {
    return (x << r) | (x >> (32 - r));
}

// Threefry-2x32, 20 rounds (jax_threefry_partitionable=True layout, verified R1).
__device__ __forceinline__ void threefry2x32(unsigned k0, unsigned k1,
                                             unsigned x0, unsigned x1,
                                             unsigned& o0, unsigned& o1) {
    unsigned ks2 = k0 ^ k1 ^ 0x1BD11BDAu;
    x0 += k0; x1 += k1;
#define TF_R(r) { x0 += x1; x1 = rotl32(x1, r); x1 ^= x0; }
    TF_R(13) TF_R(15) TF_R(26) TF_R(6)   x0 += k1;  x1 += ks2 + 1u;
    TF_R(17) TF_R(29) TF_R(16) TF_R(24)  x0 += ks2; x1 += k0 + 2u;
    TF_R(13) TF_R(15) TF_R(26) TF_R(6)   x0 += k0;  x1 += k1 + 3u;
    TF_R(17) TF_R(29) TF_R(16) TF_R(24)  x0 += k1;  x1 += ks2 + 4u;
    TF_R(13) TF_R(15) TF_R(26) TF_R(6)   x0 += ks2; x1 += k0 + 5u;
#undef TF_R
    o0 = x0; o1 = x1;
}

__device__ __forceinline__ float dropout_val(const float* __restrict__ ue,
                                             const float* __restrict__ ie,
                                             int i, unsigned bits) {
    float src = (i < NU * D) ? ue[i] : ie[i - NU * D];
    float u = __uint_as_float((bits >> 9) | 0x3f800000u) - 1.0f;
    return (u < 0.8f) ? (src / 0.8f) : 0.0f;
}

// x0 = dropout(concat(ue,ie)), stored fp16 (gather copy; also the combine seed).
__global__ void k_dropout_init(const float* __restrict__ ue,
                               const float* __restrict__ ie,
                               half_t* __restrict__ x0h) {
    int j = blockIdx.x * blockDim.x + threadIdx.x;   // [0, XH)
    if (j >= XH) return;
    unsigned o0, o1, b0, b1;
    threefry2x32(0u, 42u, 0u, (unsigned)j, o0, o1);        b0 = o0 ^ o1;
    threefry2x32(0u, 42u, 0u, (unsigned)(j + XH), o0, o1); b1 = o0 ^ o1;
    x0h[j]      = (half_t)dropout_val(ue, ie, j, b0);
    x0h[j + XH] = (half_t)dropout_val(ue, ie, j + XH, b1);
}

// Pass A: bin 4096 edges/block into 147 buckets (bucket = row>>10).
// LDS counters -> block-local offsets; one padded global atomic per bucket per
// block; records land in block-private dense runs (~28 recs = 224B each).
__global__ void __launch_bounds__(BIN_T) k_bin(const int* __restrict__ rows,
                                               const int* __restrict__ cols,
                                               const float* __restrict__ vals,
                                               int2* __restrict__ stg,
                                               int* __restrict__ pcnt) {
    __shared__ int lcnt[NB];
    __shared__ int gbase[NB];
    int tid = threadIdx.x;
    for (int i = tid; i < NB; i += BIN_T) lcnt[i] = 0;
    __syncthreads();
    int base = blockIdx.x * BIN_CHUNK;
    int lp[BIN_U];          // (bucket<<13) | loff, or -1 for tail
    int2 rec[BIN_U];
    #pragma unroll
    for (int u = 0; u < BIN_U; ++u) {
        int idx = base + u * BIN_T + tid;
        if (idx < E) {
            int row = rows[idx];
            int col = cols[idx];
            float v = vals[idx];
            unsigned q = min(__float2int_rn(v * 65536.f), 16383);
            int b = row >> 10;
            int loff = atomicAdd(&lcnt[b], 1);
            lp[u] = (b << 13) | loff;               // loff < 4096 < 8192
            rec[u] = make_int2((int)((q << 18) | (unsigned)col), row);
        } else {
            lp[u] = -1;
        }
    }
    __syncthreads();
    for (int i = tid; i < NB; i += BIN_T)
        gbase[i] = atomicAdd(&pcnt[i * 16], lcnt[i]);   // 64B-padded counters
    __syncthreads();
    #pragma unroll
    for (int u = 0; u < BIN_U; ++u) {
        if (lp[u] >= 0) {
            int b = lp[u] >> 13;
            int pos = gbase[b] + (lp[u] & 8191);
            if (pos < BPC) stg[(size_t)b * BPC + pos] = rec[u];
        }
    }
}

// Exclusive scan of 147 bucket counts (single wave); rp[NN] = E sentinel.
__global__ void k_bscan(const int* __restrict__ pcnt, int* __restrict__ bbase,
                        int* __restrict__ rp) {
    int lane = threadIdx.x;          // 64 threads
    int carry = 0;
    for (int base = 0; base < NB; base += 64) {
        int i = base + lane;
        int v = (i < NB) ? pcnt[i * 16] : 0;
        int x = v;
        #pragma unroll
        for (int d = 1; d < 64; d <<= 1) {
            int y = __shfl_up(x, d);
            if (lane >= d) x += y;
        }
        if (i < NB) bbase[i] = carry + x - v;   // exclusive
        carry += __shfl(x, 63);
    }
    if (lane == 0) rp[NN] = E;
}

// Pass B: one block per bucket. Hist 1024 rows in LDS, scan, write rp, then
// scatter records into the bucket's dense [bb, bb+tot) region of ev.
__global__ void __launch_bounds__(1024) k_bsort(const int2* __restrict__ stg,
                                                const int* __restrict__ pcnt,
                                                const int* __restrict__ bbase,
                                                int* __restrict__ rp,
                                                unsigned* __restrict__ ev) {
    __shared__ int cnt[1024];
    __shared__ int wsum[16];
    int b = blockIdx.x;
    int t = threadIdx.x;
    cnt[t] = 0;
    __syncthreads();
    int tot = min(pcnt[b * 16], BPC);
    int bb = bbase[b];
    const int2* s = stg + (size_t)b * BPC;
    for (int i = t; i < tot; i += 1024)
        atomicAdd(&cnt[s[i].y & 1023], 1);
    __syncthreads();
    // Block-wide exclusive scan of cnt[1024].
    int v = cnt[t];
    int lane = t & 63, w = t >> 6;
    int x = v;
    #pragma unroll
    for (int d = 1; d < 64; d <<= 1) {
        int y = __shfl_up(x, d);
        if (lane >= d) x += y;
    }
    if (lane == 63) wsum[w] = x;
    __syncthreads();
    if (w == 0 && lane < 16) {
        int sv = wsum[lane];
        #pragma unroll
        for (int d = 1; d < 16; d <<= 1) {
            int y = __shfl_up(sv, d);
            if (lane >= d) sv += y;
        }
        wsum[lane] = sv;
    }
    __syncthreads();
    int excl = ((w > 0) ? wsum[w - 1] : 0) + x - v;
    int row = (b << 10) + t;
    if (row < NN) rp[row] = bb + excl;
    __syncthreads();
    cnt[t] = bb + excl;               // becomes the scatter cursor
    __syncthreads();
    for (int i = t; i < tot; i += 1024) {
        int2 r = s[i];
        int pos = atomicAdd(&cnt[r.y & 1023], 1);
        ev[pos] = (unsigned)r.x;
    }
}

// Pull SpMM over exact CSR, fp16 x. Wave = 1 row. 4 edge-groups x 16 lanes;
// lane holds 4 dims (8B fp16) -> wave gathers 4 edges x 128B = 512B per load.
// MODE 0: yh = A*xh (fp16 out). MODE 1: out_f32 = (x0h + y1h + xh + A*xh)*0.25.
template <int MODE>
__global__ void __launch_bounds__(256) k_spmm(const int* __restrict__ rp,
                                              const unsigned* __restrict__ ev,
                                              const half_t* __restrict__ xh,
                                              half_t* __restrict__ yh,
                                              const half_t* __restrict__ x0h,
                                              const half_t* __restrict__ y1h,
                                              float* __restrict__ out) {
    int row = blockIdx.x * 4 + (threadIdx.x >> 6);
    if (row >= NN) return;
    int lane = threadIdx.x & 63;
    int grp = lane >> 4;      // edge subgroup 0..3
    int sl  = lane & 15;      // dim quad: dims [4*sl, 4*sl+4)
    const float inv = 1.0f / 65536.0f;
    int s0 = rp[row];
    int cnt = rp[row + 1] - s0;
    float4 acc = make_float4(0.f, 0.f, 0.f, 0.f);
    for (int base = 0; base < cnt; base += 64) {
        int idx = base + lane;
        int pc = (idx < cnt) ? (int)ev[s0 + idx] : 0;  // coalesced; pad q=0 -> v=0
        int m = min(64, cnt - base);
        int mm = (m + 3) & ~3;
        for (int jj = 0; jj < mm; jj += 4) {
            int j = jj + grp;                          // j <= 63 always
            int pj = __shfl(pc, j);
            int   cj = pj & 0x3FFFF;
            float vj = (float)((unsigned)pj >> 18) * inv;
            const half4 xv = *(const half4*)(xh + cj * 64 + sl * 4);   // 8B
            acc.x = fmaf(vj, (float)xv.x, acc.x);
            acc.y = fmaf(vj, (float)xv.y, acc.y);
            acc.z = fmaf(vj, (float)xv.z, acc.z);
            acc.w = fmaf(vj, (float)xv.w, acc.w);
        }
    }
    // Reduce the 4 edge-groups: butterfly over lane bits 16 and 32.
    #pragma unroll
    for (int mask = 16; mask <= 32; mask <<= 1) {
        acc.x += __shfl_xor(acc.x, mask);
        acc.y += __shfl_xor(acc.y, mask);
        acc.z += __shfl_xor(acc.z, mask);
        acc.w += __shfl_xor(acc.w, mask);
    }
    if (grp == 0) {
        int o = row * 64 + sl * 4;
        if (MODE == 0) {
            half4 st;
            st.x = (half_t)acc.x; st.y = (half_t)acc.y;
            st.z = (half_t)acc.z; st.w = (half_t)acc.w;
            *(half4*)(yh + o) = st;
        } else {
            const half4 a0 = *(const half4*)(x0h + o);   // X0 (fp16)
            const half4 a1 = *(const half4*)(y1h + o);   // Y1 (fp16)
            const half4 a2 = *(const half4*)(xh + o);    // Y2 (linear read)
            float4 r;
            r.x = ((float)a0.x + (float)a1.x + (float)a2.x + acc.x) * 0.25f;
            r.y = ((float)a0.y + (float)a1.y + (float)a2.y + acc.y) * 0.25f;
            r.z = ((float)a0.z + (float)a1.z + (float)a2.z + acc.z) * 0.25f;
            r.w = ((float)a0.w + (float)a1.w + (float)a2.w + acc.w) * 0.25f;
            *(float4*)(out + o) = r;
        }
    }
}

extern "C" void kernel_launch(void* const* d_in, const int* in_sizes, int n_in,
                              void* d_out, int out_size, void* d_ws, size_t ws_size,
                              hipStream_t stream) {
    const float* ue   = (const float*)d_in[0];
    const float* ie   = (const float*)d_in[1];
    const int*   rows = (const int*)d_in[2];
    const int*   cols = (const int*)d_in[3];
    const float* vals = (const float*)d_in[4];
    float* out = (float*)d_out;

    // Workspace: X0h [XN fp16 = 19.2MB] | Y1h [19.2MB] | Y2h [19.2MB]
    //   (stg aliases Y1h..Y2h: NB*BPC*8B = 28.2MB < 38.4MB, dead before spmm
    //    layer 1 writes Y1h) | ev [E*4 = 9.6MB] | rp [NN+1] | pcnt [NB*16]
    //   | bbase [NB].  Total ~68 MB (was 87 MB in R8).
    half_t*   X0h   = (half_t*)d_ws;
    half_t*   Y1h   = X0h + XN;
    half_t*   Y2h   = Y1h + XN;
    int2*     stg   = (int2*)Y1h;
    unsigned* ev    = (unsigned*)(Y2h + XN);
    int*      rp    = (int*)(ev + E);
    int*      pcnt  = rp + NN + 4;
    int*      bbase = pcnt + NB * 16;

    (void)hipMemsetAsync(pcnt, 0, (NB * 16 + NB) * sizeof(int), stream);
    k_dropout_init<<<(XH + 255) / 256, 256, 0, stream>>>(ue, ie, X0h);
    k_bin<<<(E + BIN_CHUNK - 1) / BIN_CHUNK, BIN_T, 0, stream>>>(rows, cols, vals, stg, pcnt);
    k_bscan<<<1, 64, 0, stream>>>(pcnt, bbase, rp);
    k_bsort<<<NB, 1024, 0, stream>>>(stg, pcnt, bbase, rp, ev);

    int sgrid = (NN + 3) / 4;
    k_spmm<0><<<sgrid, 256, 0, stream>>>(rp, ev, X0h, Y1h, nullptr, nullptr, nullptr); // Y1=A*X0
    k_spmm<0><<<sgrid, 256, 0, stream>>>(rp, ev, Y1h, Y2h, nullptr, nullptr, nullptr); // Y2=A*Y1
    k_spmm<1><<<sgrid, 256, 0, stream>>>(rp, ev, Y2h, nullptr, X0h, Y1h, out);         // combine
}

// Round 2
// 343.141 us; speedup vs baseline: 1.3145x; 1.1050x over previous
//
#include <hip/hip_runtime.h>

// LightGCN: x0 = dropout(concat(user,item)); out = (x0 + A x0 + A^2 x0 + A^3 x0)/4
// R10: MLP-widened SpMM gather.
//   R9 post-mortem: halving gather bytes (fp16) halved FETCH_SIZE exactly
//   (336->162MB) but time only fell 26% and delivered BW DROPPED to 2.7TB/s
//   -> the gather is latency/concurrency-bound (Little's law: ~560KB must be
//   in flight to sustain 2.7TB/s at ~500cy), not bandwidth-bound.
//   Fix: 8 edge-groups x 8 lanes, lane loads half8 (16B) -> 8 edges in flight
//   per wave-instruction; plus 2x hand-unroll -> 16 edges / 2KB in flight per
//   wave (4x R9's MLP). Same bytes, half the load+shfl instructions per edge.
// fp16 intermediates (R9): gather granule 128B, working set 19.2MB.
// CSR build (R8, unchanged): two-level counting sort (k_bin buckets row>>10,
// k_bsort per-bucket LDS hist+scan -> rp, dense ev scatter).

static constexpr int NU = 100000;
static constexpr int NI = 50000;
static constexpr int NN = NU + NI;       // 150000
static constexpr int D  = 64;
static constexpr int E  = 2400000;
static constexpr int XN = NN * D;        // 9,600,000
static constexpr int XH = XN / 2;        // 4,800,000
static constexpr int NB = (NN + 1023) >> 10;   // 147 buckets
static constexpr int BPC = 24000;        // bucket staging cap (mean 16327, +59 sigma)
static constexpr int BIN_T = 256;
static constexpr int BIN_U = 16;
static constexpr int BIN_CHUNK = BIN_T * BIN_U;   // 4096

typedef _Float16 half_t;
typedef _Float16 half8 __attribute__((ext_vector_type(8)));

__device__ __forceinline__ unsigned rotl32(unsigned x, int r) {
    return (x << r) | (x >> (32 - r));
}

// Threefry-2x32, 20 rounds (jax_threefry_partitionable=True layout, verified R1).
__device__ __forceinline__ void threefry2x32(unsigned k0, unsigned k1,
                                             unsigned x0, unsigned x1,
                                             unsigned& o0, unsigned& o1) {
    unsigned ks2 = k0 ^ k1 ^ 0x1BD11BDAu;
    x0 += k0; x1 += k1;
#define TF_R(r) { x0 += x1; x1 = rotl32(x1, r); x1 ^= x0; }
    TF_R(13) TF_R(15) TF_R(26) TF_R(6)   x0 += k1;  x1 += ks2 + 1u;
    TF_R(17) TF_R(29) TF_R(16) TF_R(24)  x0 += ks2; x1 += k0 + 2u;
    TF_R(13) TF_R(15) TF_R(26) TF_R(6)   x0 += k0;  x1 += k1 + 3u;
    TF_R(17) TF_R(29) TF_R(16) TF_R(24)  x0 += k1;  x1 += ks2 + 4u;
    TF_R(13) TF_R(15) TF_R(26) TF_R(6)   x0 += ks2; x1 += k0 + 5u;
#undef TF_R
    o0 = x0; o1 = x1;
}

__device__ __forceinline__ float dropout_val(const float* __restrict__ ue,
                                             const float* __restrict__ ie,
                                             int i, unsigned bits) {
    float src = (i < NU * D) ? ue[i] : ie[i - NU * D];
    float u = __uint_as_float((bits >> 9) | 0x3f800000u) - 1.0f;
    return (u < 0.8f) ? (src / 0.8f) : 0.0f;
}

// x0 = dropout(concat(ue,ie)), stored fp16 (gather copy; also the combine seed).
__global__ void k_dropout_init(const float* __restrict__ ue,
                               const float* __restrict__ ie,
                               half_t* __restrict__ x0h) {
    int j = blockIdx.x * blockDim.x + threadIdx.x;   // [0, XH)
    if (j >= XH) return;
    unsigned o0, o1, b0, b1;
    threefry2x32(0u, 42u, 0u, (unsigned)j, o0, o1);        b0 = o0 ^ o1;
    threefry2x32(0u, 42u, 0u, (unsigned)(j + XH), o0, o1); b1 = o0 ^ o1;
    x0h[j]      = (half_t)dropout_val(ue, ie, j, b0);
    x0h[j + XH] = (half_t)dropout_val(ue, ie, j + XH, b1);
}

// Pass A: bin 4096 edges/block into 147 buckets (bucket = row>>10).
// LDS counters -> block-local offsets; one padded global atomic per bucket per
// block; records land in block-private dense runs (~28 recs = 224B each).
__global__ void __launch_bounds__(BIN_T) k_bin(const int* __restrict__ rows,
                                               const int* __restrict__ cols,
                                               const float* __restrict__ vals,
                                               int2* __restrict__ stg,
                                               int* __restrict__ pcnt) {
    __shared__ int lcnt[NB];
    __shared__ int gbase[NB];
    int tid = threadIdx.x;
    for (int i = tid; i < NB; i += BIN_T) lcnt[i] = 0;
    __syncthreads();
    int base = blockIdx.x * BIN_CHUNK;
    int lp[BIN_U];          // (bucket<<13) | loff, or -1 for tail
    int2 rec[BIN_U];
    #pragma unroll
    for (int u = 0; u < BIN_U; ++u) {
        int idx = base + u * BIN_T + tid;
        if (idx < E) {
            int row = rows[idx];
            int col = cols[idx];
            float v = vals[idx];
            unsigned q = min(__float2int_rn(v * 65536.f), 16383);
            int b = row >> 10;
            int loff = atomicAdd(&lcnt[b], 1);
            lp[u] = (b << 13) | loff;               // loff < 4096 < 8192
            rec[u] = make_int2((int)((q << 18) | (unsigned)col), row);
        } else {
            lp[u] = -1;
        }
    }
    __syncthreads();
    for (int i = tid; i < NB; i += BIN_T)
        gbase[i] = atomicAdd(&pcnt[i * 16], lcnt[i]);   // 64B-padded counters
    __syncthreads();
    #pragma unroll
    for (int u = 0; u < BIN_U; ++u) {
        if (lp[u] >= 0) {
            int b = lp[u] >> 13;
            int pos = gbase[b] + (lp[u] & 8191);
            if (pos < BPC) stg[(size_t)b * BPC + pos] = rec[u];
        }
    }
}

// Exclusive scan of 147 bucket counts (single wave); rp[NN] = E sentinel.
__global__ void k_bscan(const int* __restrict__ pcnt, int* __restrict__ bbase,
                        int* __restrict__ rp) {
    int lane = threadIdx.x;          // 64 threads
    int carry = 0;
    for (int base = 0; base < NB; base += 64) {
        int i = base + lane;
        int v = (i < NB) ? pcnt[i * 16] : 0;
        int x = v;
        #pragma unroll
        for (int d = 1; d < 64; d <<= 1) {
            int y = __shfl_up(x, d);
            if (lane >= d) x += y;
        }
        if (i < NB) bbase[i] = carry + x - v;   // exclusive
        carry += __shfl(x, 63);
    }
    if (lane == 0) rp[NN] = E;
}

// Pass B: one block per bucket. Hist 1024 rows in LDS, scan, write rp, then
// scatter records into the bucket's dense [bb, bb+tot) region of ev.
__global__ void __launch_bounds__(1024) k_bsort(const int2* __restrict__ stg,
                                                const int* __restrict__ pcnt,
                                                const int* __restrict__ bbase,
                                                int* __restrict__ rp,
                                                unsigned* __restrict__ ev) {
    __shared__ int cnt[1024];
    __shared__ int wsum[16];
    int b = blockIdx.x;
    int t = threadIdx.x;
    cnt[t] = 0;
    __syncthreads();
    int tot = min(pcnt[b * 16], BPC);
    int bb = bbase[b];
    const int2* s = stg + (size_t)b * BPC;
    for (int i = t; i < tot; i += 1024)
        atomicAdd(&cnt[s[i].y & 1023], 1);
    __syncthreads();
    // Block-wide exclusive scan of cnt[1024].
    int v = cnt[t];
    int lane = t & 63, w = t >> 6;
    int x = v;
    #pragma unroll
    for (int d = 1; d < 64; d <<= 1) {
        int y = __shfl_up(x, d);
        if (lane >= d) x += y;
    }
    if (lane == 63) wsum[w] = x;
    __syncthreads();
    if (w == 0 && lane < 16) {
        int sv = wsum[lane];
        #pragma unroll
        for (int d = 1; d < 16; d <<= 1) {
            int y = __shfl_up(sv, d);
            if (lane >= d) sv += y;
        }
        wsum[lane] = sv;
    }
    __syncthreads();
    int excl = ((w > 0) ? wsum[w - 1] : 0) + x - v;
    int row = (b << 10) + t;
    if (row < NN) rp[row] = bb + excl;
    __syncthreads();
    cnt[t] = bb + excl;               // becomes the scatter cursor
    __syncthreads();
    for (int i = t; i < tot; i += 1024) {
        int2 r = s[i];
        int pos = atomicAdd(&cnt[r.y & 1023], 1);
        ev[pos] = (unsigned)r.x;
    }
}

// Pull SpMM over exact CSR, fp16 x. Wave = 1 row. 8 edge-groups x 8 lanes;
// lane holds 8 dims (16B fp16). Inner loop 2x-unrolled: 16 edges / 2KB in
// flight per wave before the fma wait (4x the R9 MLP).
// MODE 0: yh = A*xh (fp16 out). MODE 1: out_f32 = (x0h + y1h + xh + A*xh)*0.25.
template <int MODE>
__global__ void __launch_bounds__(256) k_spmm(const int* __restrict__ rp,
                                              const unsigned* __restrict__ ev,
                                              const half_t* __restrict__ xh,
                                              half_t* __restrict__ yh,
                                              const half_t* __restrict__ x0h,
                                              const half_t* __restrict__ y1h,
                                              float* __restrict__ out) {
    int row = blockIdx.x * 4 + (threadIdx.x >> 6);
    if (row >= NN) return;
    int lane = threadIdx.x & 63;
    int grp = lane >> 3;      // edge subgroup 0..7
    int sl  = lane & 7;       // dim octet: dims [8*sl, 8*sl+8)
    const float inv = 1.0f / 65536.0f;
    int s0 = rp[row];
    int cnt = rp[row + 1] - s0;
    float acc[8] = {0.f, 0.f, 0.f, 0.f, 0.f, 0.f, 0.f, 0.f};
    for (int base = 0; base < cnt; base += 64) {
        int idx = base + lane;
        int pc = (idx < cnt) ? (int)ev[s0 + idx] : 0;  // coalesced; pad q=0 -> v=0
        int m = min(64, cnt - base);
        int mm = (m + 15) & ~15;                       // <= 64; padded lanes pc=0
        for (int jj = 0; jj < mm; jj += 16) {
            int pj0 = __shfl(pc, jj + grp);
            int pj1 = __shfl(pc, jj + 8 + grp);
            int   c0 = pj0 & 0x3FFFF;
            float v0 = (float)((unsigned)pj0 >> 18) * inv;
            int   c1 = pj1 & 0x3FFFF;
            float v1 = (float)((unsigned)pj1 >> 18) * inv;
            const half8 xa = *(const half8*)(xh + c0 * 64 + sl * 8);   // 16B
            const half8 xb = *(const half8*)(xh + c1 * 64 + sl * 8);   // 16B
            #pragma unroll
            for (int k = 0; k < 8; ++k) acc[k] = fmaf(v0, (float)xa[k], acc[k]);
            #pragma unroll
            for (int k = 0; k < 8; ++k) acc[k] = fmaf(v1, (float)xb[k], acc[k]);
        }
    }
    // Reduce the 8 edge-groups: butterfly over lane bits 8, 16, 32.
    #pragma unroll
    for (int mask = 8; mask <= 32; mask <<= 1) {
        #pragma unroll
        for (int k = 0; k < 8; ++k) acc[k] += __shfl_xor(acc[k], mask);
    }
    if (grp == 0) {
        int o = row * 64 + sl * 8;
        if (MODE == 0) {
            half8 st;
            #pragma unroll
            for (int k = 0; k < 8; ++k) st[k] = (half_t)acc[k];
            *(half8*)(yh + o) = st;
        } else {
            const half8 a0 = *(const half8*)(x0h + o);   // X0 (fp16)
            const half8 a1 = *(const half8*)(y1h + o);   // Y1 (fp16)
            const half8 a2 = *(const half8*)(xh + o);    // Y2 (linear read)
            float r[8];
            #pragma unroll
            for (int k = 0; k < 8; ++k)
                r[k] = ((float)a0[k] + (float)a1[k] + (float)a2[k] + acc[k]) * 0.25f;
            *(float4*)(out + o)     = make_float4(r[0], r[1], r[2], r[3]);
            *(float4*)(out + o + 4) = make_float4(r[4], r[5], r[6], r[7]);
        }
    }
}

extern "C" void kernel_launch(void* const* d_in, const int* in_sizes, int n_in,
                              void* d_out, int out_size, void* d_ws, size_t ws_size,
                              hipStream_t stream) {
    const float* ue   = (const float*)d_in[0];
    const float* ie   = (const float*)d_in[1];
    const int*   rows = (const int*)d_in[2];
    const int*   cols = (const int*)d_in[3];
    const float* vals = (const float*)d_in[4];
    float* out = (float*)d_out;

    // Workspace: X0h [XN fp16 = 19.2MB] | Y1h [19.2MB] | Y2h [19.2MB]
    //   (stg aliases Y1h..Y2h: NB*BPC*8B = 28.2MB < 38.4MB, dead before spmm
    //    layer 1 writes Y1h) | ev [E*4 = 9.6MB] | rp [NN+1] | pcnt [NB*16]
    //   | bbase [NB].  Total ~68 MB.
    half_t*   X0h   = (half_t*)d_ws;
    half_t*   Y1h   = X0h + XN;
    half_t*   Y2h   = Y1h + XN;
    int2*     stg   = (int2*)Y1h;
    unsigned* ev    = (unsigned*)(Y2h + XN);
    int*      rp    = (int*)(ev + E);
    int*      pcnt  = rp + NN + 4;
    int*      bbase = pcnt + NB * 16;

    (void)hipMemsetAsync(pcnt, 0, (NB * 16 + NB) * sizeof(int), stream);
    k_dropout_init<<<(XH + 255) / 256, 256, 0, stream>>>(ue, ie, X0h);
    k_bin<<<(E + BIN_CHUNK - 1) / BIN_CHUNK, BIN_T, 0, stream>>>(rows, cols, vals, stg, pcnt);
    k_bscan<<<1, 64, 0, stream>>>(pcnt, bbase, rp);
    k_bsort<<<NB, 1024, 0, stream>>>(stg, pcnt, bbase, rp, ev);

    int sgrid = (NN + 3) / 4;
    k_spmm<0><<<sgrid, 256, 0, stream>>>(rp, ev, X0h, Y1h, nullptr, nullptr, nullptr); // Y1=A*X0
    k_spmm<0><<<sgrid, 256, 0, stream>>>(rp, ev, Y1h, Y2h, nullptr, nullptr, nullptr); // Y2=A*Y1
    k_spmm<1><<<sgrid, 256, 0, stream>>>(rp, ev, Y2h, nullptr, X0h, Y1h, out);         // combine
}

// Round 3
// 318.645 us; speedup vs baseline: 1.4156x; 1.0769x over previous
//
#include <hip/hip_runtime.h>

// LightGCN: x0 = dropout(concat(user,item)); out = (x0 + A x0 + A^2 x0 + A^3 x0)/4
// R11: group-per-row SpMM — delete the butterfly reduce.
//   R10 post-mortem: VALUBusy 44->67% while BW stalled at 3.1TB/s; per-row
//   fixed cost (24 shfl + 24 add butterfly + setup) exceeded useful work for
//   the average 16-edge row. New decomposition: wave = 8 rows, 8-lane group
//   owns a row (lane l = dims [8l,8l+8)). Edge codes loaded by the group's
//   own lanes (adjacent rows -> adjacent ev segments), shfl-broadcast within
//   the group; acc IS the output — no cross-group reduce, 8x fewer waves.
//   MLP kept: 4x unrolled j-loop = up to 8 independent 16B gathers per group.
// fp16 intermediates (R9): gather granule 128B, working set 19.2MB.
// CSR build (R8, unchanged): two-level counting sort (k_bin buckets row>>10,
// k_bsort per-bucket LDS hist+scan -> rp, dense ev scatter).

static constexpr int NU = 100000;
static constexpr int NI = 50000;
static constexpr int NN = NU + NI;       // 150000
static constexpr int D  = 64;
static constexpr int E  = 2400000;
static constexpr int XN = NN * D;        // 9,600,000
static constexpr int XH = XN / 2;        // 4,800,000
static constexpr int NB = (NN + 1023) >> 10;   // 147 buckets
static constexpr int BPC = 24000;        // bucket staging cap (mean 16327, +59 sigma)
static constexpr int BIN_T = 256;
static constexpr int BIN_U = 16;
static constexpr int BIN_CHUNK = BIN_T * BIN_U;   // 4096

typedef _Float16 half_t;
typedef _Float16 half8 __attribute__((ext_vector_type(8)));

__device__ __forceinline__ unsigned rotl32(unsigned x, int r) {
    return (x << r) | (x >> (32 - r));
}

// Threefry-2x32, 20 rounds (jax_threefry_partitionable=True layout, verified R1).
__device__ __forceinline__ void threefry2x32(unsigned k0, unsigned k1,
                                             unsigned x0, unsigned x1,
                                             unsigned& o0, unsigned& o1) {
    unsigned ks2 = k0 ^ k1 ^ 0x1BD11BDAu;
    x0 += k0; x1 += k1;
#define TF_R(r) { x0 += x1; x1 = rotl32(x1, r); x1 ^= x0; }
    TF_R(13) TF_R(15) TF_R(26) TF_R(6)   x0 += k1;  x1 += ks2 + 1u;
    TF_R(17) TF_R(29) TF_R(16) TF_R(24)  x0 += ks2; x1 += k0 + 2u;
    TF_R(13) TF_R(15) TF_R(26) TF_R(6)   x0 += k0;  x1 += k1 + 3u;
    TF_R(17) TF_R(29) TF_R(16) TF_R(24)  x0 += k1;  x1 += ks2 + 4u;
    TF_R(13) TF_R(15) TF_R(26) TF_R(6)   x0 += ks2; x1 += k0 + 5u;
#undef TF_R
    o0 = x0; o1 = x1;
}

__device__ __forceinline__ float dropout_val(const float* __restrict__ ue,
                                             const float* __restrict__ ie,
                                             int i, unsigned bits) {
    float src = (i < NU * D) ? ue[i] : ie[i - NU * D];
    float u = __uint_as_float((bits >> 9) | 0x3f800000u) - 1.0f;
    return (u < 0.8f) ? (src / 0.8f) : 0.0f;
}

// x0 = dropout(concat(ue,ie)), stored fp16 (gather copy; also the combine seed).
__global__ void k_dropout_init(const float* __restrict__ ue,
                               const float* __restrict__ ie,
                               half_t* __restrict__ x0h) {
    int j = blockIdx.x * blockDim.x + threadIdx.x;   // [0, XH)
    if (j >= XH) return;
    unsigned o0, o1, b0, b1;
    threefry2x32(0u, 42u, 0u, (unsigned)j, o0, o1);        b0 = o0 ^ o1;
    threefry2x32(0u, 42u, 0u, (unsigned)(j + XH), o0, o1); b1 = o0 ^ o1;
    x0h[j]      = (half_t)dropout_val(ue, ie, j, b0);
    x0h[j + XH] = (half_t)dropout_val(ue, ie, j + XH, b1);
}

// Pass A: bin 4096 edges/block into 147 buckets (bucket = row>>10).
// LDS counters -> block-local offsets; one padded global atomic per bucket per
// block; records land in block-private dense runs (~28 recs = 224B each).
__global__ void __launch_bounds__(BIN_T) k_bin(const int* __restrict__ rows,
                                               const int* __restrict__ cols,
                                               const float* __restrict__ vals,
                                               int2* __restrict__ stg,
                                               int* __restrict__ pcnt) {
    __shared__ int lcnt[NB];
    __shared__ int gbase[NB];
    int tid = threadIdx.x;
    for (int i = tid; i < NB; i += BIN_T) lcnt[i] = 0;
    __syncthreads();
    int base = blockIdx.x * BIN_CHUNK;
    int lp[BIN_U];          // (bucket<<13) | loff, or -1 for tail
    int2 rec[BIN_U];
    #pragma unroll
    for (int u = 0; u < BIN_U; ++u) {
        int idx = base + u * BIN_T + tid;
        if (idx < E) {
            int row = rows[idx];
            int col = cols[idx];
            float v = vals[idx];
            unsigned q = min(__float2int_rn(v * 65536.f), 16383);
            int b = row >> 10;
            int loff = atomicAdd(&lcnt[b], 1);
            lp[u] = (b << 13) | loff;               // loff < 4096 < 8192
            rec[u] = make_int2((int)((q << 18) | (unsigned)col), row);
        } else {
            lp[u] = -1;
        }
    }
    __syncthreads();
    for (int i = tid; i < NB; i += BIN_T)
        gbase[i] = atomicAdd(&pcnt[i * 16], lcnt[i]);   // 64B-padded counters
    __syncthreads();
    #pragma unroll
    for (int u = 0; u < BIN_U; ++u) {
        if (lp[u] >= 0) {
            int b = lp[u] >> 13;
            int pos = gbase[b] + (lp[u] & 8191);
            if (pos < BPC) stg[(size_t)b * BPC + pos] = rec[u];
        }
    }
}

// Exclusive scan of 147 bucket counts (single wave); rp[NN] = E sentinel.
__global__ void k_bscan(const int* __restrict__ pcnt, int* __restrict__ bbase,
                        int* __restrict__ rp) {
    int lane = threadIdx.x;          // 64 threads
    int carry = 0;
    for (int base = 0; base < NB; base += 64) {
        int i = base + lane;
        int v = (i < NB) ? pcnt[i * 16] : 0;
        int x = v;
        #pragma unroll
        for (int d = 1; d < 64; d <<= 1) {
            int y = __shfl_up(x, d);
            if (lane >= d) x += y;
        }
        if (i < NB) bbase[i] = carry + x - v;   // exclusive
        carry += __shfl(x, 63);
    }
    if (lane == 0) rp[NN] = E;
}

// Pass B: one block per bucket. Hist 1024 rows in LDS, scan, write rp, then
// scatter records into the bucket's dense [bb, bb+tot) region of ev.
__global__ void __launch_bounds__(1024) k_bsort(const int2* __restrict__ stg,
                                                const int* __restrict__ pcnt,
                                                const int* __restrict__ bbase,
                                                int* __restrict__ rp,
                                                unsigned* __restrict__ ev) {
    __shared__ int cnt[1024];
    __shared__ int wsum[16];
    int b = blockIdx.x;
    int t = threadIdx.x;
    cnt[t] = 0;
    __syncthreads();
    int tot = min(pcnt[b * 16], BPC);
    int bb = bbase[b];
    const int2* s = stg + (size_t)b * BPC;
    for (int i = t; i < tot; i += 1024)
        atomicAdd(&cnt[s[i].y & 1023], 1);
    __syncthreads();
    // Block-wide exclusive scan of cnt[1024].
    int v = cnt[t];
    int lane = t & 63, w = t >> 6;
    int x = v;
    #pragma unroll
    for (int d = 1; d < 64; d <<= 1) {
        int y = __shfl_up(x, d);
        if (lane >= d) x += y;
    }
    if (lane == 63) wsum[w] = x;
    __syncthreads();
    if (w == 0 && lane < 16) {
        int sv = wsum[lane];
        #pragma unroll
        for (int d = 1; d < 16; d <<= 1) {
            int y = __shfl_up(sv, d);
            if (lane >= d) sv += y;
        }
        wsum[lane] = sv;
    }
    __syncthreads();
    int excl = ((w > 0) ? wsum[w - 1] : 0) + x - v;
    int row = (b << 10) + t;
    if (row < NN) rp[row] = bb + excl;
    __syncthreads();
    cnt[t] = bb + excl;               // becomes the scatter cursor
    __syncthreads();
    for (int i = t; i < tot; i += 1024) {
        int2 r = s[i];
        int pos = atomicAdd(&cnt[r.y & 1023], 1);
        ev[pos] = (unsigned)r.x;
    }
}

// Pull SpMM over exact CSR, fp16 x. Wave = 8 rows; 8-lane group owns a row
// (lane l holds dims [8l,8l+8), 16B). Group's lanes load 8 edge codes at a
// time (adjacent rows -> near-contiguous ev reads), shfl-broadcast within the
// group, gather 128B x-row per edge. acc is final — no cross-group reduce.
// Padded edges (idx>=cnt) have code 0 -> v=0, gather x[0] (L1-hot), harmless.
// MODE 0: yh = A*xh (fp16 out). MODE 1: out_f32 = (x0h + y1h + xh + A*xh)*0.25.
template <int MODE>
__global__ void __launch_bounds__(256) k_spmm(const int* __restrict__ rp,
                                              const unsigned* __restrict__ ev,
                                              const half_t* __restrict__ xh,
                                              half_t* __restrict__ yh,
                                              const half_t* __restrict__ x0h,
                                              const half_t* __restrict__ y1h,
                                              float* __restrict__ out) {
    int wid  = threadIdx.x >> 6;             // wave in block: 0..3
    int lane = threadIdx.x & 63;
    int g    = lane >> 3;                    // group (row slot) 0..7
    int l    = lane & 7;                     // lane in group: dims [8l, 8l+8)
    int row  = blockIdx.x * 32 + wid * 8 + g;
    if (row >= NN) return;
    const float inv = 1.0f / 65536.0f;
    int s0  = rp[row];
    int cnt = rp[row + 1] - s0;
    float acc[8] = {0.f, 0.f, 0.f, 0.f, 0.f, 0.f, 0.f, 0.f};
    int gl = g << 3;                         // group's base lane
    for (int base = 0; base < cnt; base += 8) {
        int idx = base + l;
        int pc = (idx < cnt) ? (int)ev[s0 + idx] : 0;
        #pragma unroll
        for (int j = 0; j < 8; j += 2) {
            int p0 = __shfl(pc, gl | j);
            int p1 = __shfl(pc, gl | (j + 1));
            int   c0 = p0 & 0x3FFFF;
            float v0 = (float)((unsigned)p0 >> 18) * inv;
            int   c1 = p1 & 0x3FFFF;
            float v1 = (float)((unsigned)p1 >> 18) * inv;
            const half8 xa = *(const half8*)(xh + c0 * 64 + l * 8);   // 16B
            const half8 xb = *(const half8*)(xh + c1 * 64 + l * 8);   // 16B
            #pragma unroll
            for (int k = 0; k < 8; ++k) acc[k] = fmaf(v0, (float)xa[k], acc[k]);
            #pragma unroll
            for (int k = 0; k < 8; ++k) acc[k] = fmaf(v1, (float)xb[k], acc[k]);
        }
    }
    int o = row * 64 + l * 8;
    if (MODE == 0) {
        half8 st;
        #pragma unroll
        for (int k = 0; k < 8; ++k) st[k] = (half_t)acc[k];
        *(half8*)(yh + o) = st;
    } else {
        const half8 a0 = *(const half8*)(x0h + o);   // X0 (fp16)
        const half8 a1 = *(const half8*)(y1h + o);   // Y1 (fp16)
        const half8 a2 = *(const half8*)(xh + o);    // Y2 (linear read)
        float r[8];
        #pragma unroll
        for (int k = 0; k < 8; ++k)
            r[k] = ((float)a0[k] + (float)a1[k] + (float)a2[k] + acc[k]) * 0.25f;
        *(float4*)(out + o)     = make_float4(r[0], r[1], r[2], r[3]);
        *(float4*)(out + o + 4) = make_float4(r[4], r[5], r[6], r[7]);
    }
}

extern "C" void kernel_launch(void* const* d_in, const int* in_sizes, int n_in,
                              void* d_out, int out_size, void* d_ws, size_t ws_size,
                              hipStream_t stream) {
    const float* ue   = (const float*)d_in[0];
    const float* ie   = (const float*)d_in[1];
    const int*   rows = (const int*)d_in[2];
    const int*   cols = (const int*)d_in[3];
    const float* vals = (const float*)d_in[4];
    float* out = (float*)d_out;

    // Workspace: X0h [XN fp16 = 19.2MB] | Y1h [19.2MB] | Y2h [19.2MB]
    //   (stg aliases Y1h..Y2h: NB*BPC*8B = 28.2MB < 38.4MB, dead before spmm
    //    layer 1 writes Y1h) | ev [E*4 = 9.6MB] | rp [NN+1] | pcnt [NB*16]
    //   | bbase [NB].  Total ~68 MB.
    half_t*   X0h   = (half_t*)d_ws;
    half_t*   Y1h   = X0h + XN;
    half_t*   Y2h   = Y1h + XN;
    int2*     stg   = (int2*)Y1h;
    unsigned* ev    = (unsigned*)(Y2h + XN);
    int*      rp    = (int*)(ev + E);
    int*      pcnt  = rp + NN + 4;
    int*      bbase = pcnt + NB * 16;

    (void)hipMemsetAsync(pcnt, 0, (NB * 16 + NB) * sizeof(int), stream);
    k_dropout_init<<<(XH + 255) / 256, 256, 0, stream>>>(ue, ie, X0h);
    k_bin<<<(E + BIN_CHUNK - 1) / BIN_CHUNK, BIN_T, 0, stream>>>(rows, cols, vals, stg, pcnt);
    k_bscan<<<1, 64, 0, stream>>>(pcnt, bbase, rp);
    k_bsort<<<NB, 1024, 0, stream>>>(stg, pcnt, bbase, rp, ev);

    int sgrid = (NN + 31) / 32;   // 32 rows per block (4 waves x 8 rows)
    k_spmm<0><<<sgrid, 256, 0, stream>>>(rp, ev, X0h, Y1h, nullptr, nullptr, nullptr); // Y1=A*X0
    k_spmm<0><<<sgrid, 256, 0, stream>>>(rp, ev, Y1h, Y2h, nullptr, nullptr, nullptr); // Y2=A*Y1
    k_spmm<1><<<sgrid, 256, 0, stream>>>(rp, ev, Y2h, nullptr, X0h, Y1h, out);         // combine
}

// Round 4
// 301.227 us; speedup vs baseline: 1.4974x; 1.0578x over previous
//
#include <hip/hip_runtime.h>

// LightGCN: x0 = dropout(concat(user,item)); out = (x0 + A x0 + A^2 x0 + A^3 x0)/4
// R12: (a) spmm batch-8 gather issue + ev prefetch. R11 post-mortem: VALUBusy
//   fell to 30%, BW 3.78TB/s, nothing saturated -> still per-lane MLP-bound;
//   asm kept only ~2 gathers in flight (VGPR=48). Now: 8 shfl -> 8 independent
//   half8 loads -> fmas (8 outstanding/lane), and the next ev batch is loaded
//   before the fma block (latency hidden under gathers).
// (b) preproc: k_bscan folded into k_bsort (per-block redundant 147-scan,
//   1 wave); dropout fused into k_bin as block-range split (bin blocks first,
//   dropout's 60MB stream overlaps bin's atomic/scatter phase).
// fp16 intermediates (R9): gather granule 128B, working set 19.2MB.
// CSR build (R8): two-level counting sort (k_bin buckets row>>10, k_bsort
// per-bucket LDS hist+scan -> rp, dense ev scatter).
// SpMM decomposition (R11): wave = 8 rows, 8-lane group owns a row.

static constexpr int NU = 100000;
static constexpr int NI = 50000;
static constexpr int NN = NU + NI;       // 150000
static constexpr int D  = 64;
static constexpr int E  = 2400000;
static constexpr int XN = NN * D;        // 9,600,000
static constexpr int XH = XN / 2;        // 4,800,000
static constexpr int NB = (NN + 1023) >> 10;   // 147 buckets
static constexpr int BPC = 24000;        // bucket staging cap (mean 16327, +59 sigma)
static constexpr int BIN_T = 256;
static constexpr int BIN_U = 16;
static constexpr int BIN_CHUNK = BIN_T * BIN_U;   // 4096
static constexpr int BGRID = (E + BIN_CHUNK - 1) / BIN_CHUNK;   // 586
static constexpr int DGRID = (XH + 255) / 256;                  // 18750

typedef _Float16 half_t;
typedef _Float16 half8 __attribute__((ext_vector_type(8)));

__device__ __forceinline__ unsigned rotl32(unsigned x, int r) {
    return (x << r) | (x >> (32 - r));
}

// Threefry-2x32, 20 rounds (jax_threefry_partitionable=True layout, verified R1).
__device__ __forceinline__ void threefry2x32(unsigned k0, unsigned k1,
                                             unsigned x0, unsigned x1,
                                             unsigned& o0, unsigned& o1) {
    unsigned ks2 = k0 ^ k1 ^ 0x1BD11BDAu;
    x0 += k0; x1 += k1;
#define TF_R(r) { x0 += x1; x1 = rotl32(x1, r); x1 ^= x0; }
    TF_R(13) TF_R(15) TF_R(26) TF_R(6)   x0 += k1;  x1 += ks2 + 1u;
    TF_R(17) TF_R(29) TF_R(16) TF_R(24)  x0 += ks2; x1 += k0 + 2u;
    TF_R(13) TF_R(15) TF_R(26) TF_R(6)   x0 += k0;  x1 += k1 + 3u;
    TF_R(17) TF_R(29) TF_R(16) TF_R(24)  x0 += k1;  x1 += ks2 + 4u;
    TF_R(13) TF_R(15) TF_R(26) TF_R(6)   x0 += ks2; x1 += k0 + 5u;
#undef TF_R
    o0 = x0; o1 = x1;
}

__device__ __forceinline__ float dropout_val(const float* __restrict__ ue,
                                             const float* __restrict__ ie,
                                             int i, unsigned bits) {
    float src = (i < NU * D) ? ue[i] : ie[i - NU * D];
    float u = __uint_as_float((bits >> 9) | 0x3f800000u) - 1.0f;
    return (u < 0.8f) ? (src / 0.8f) : 0.0f;
}

// Fused: blocks [0, BGRID) run the edge-binning pass; blocks [BGRID,
// BGRID+DGRID) run dropout-init. Bin blocks first (critical path to k_bsort);
// dropout streaming overlaps bin's atomics.
__global__ void __launch_bounds__(BIN_T) k_pre(const int* __restrict__ rows,
                                               const int* __restrict__ cols,
                                               const float* __restrict__ vals,
                                               int2* __restrict__ stg,
                                               int* __restrict__ pcnt,
                                               const float* __restrict__ ue,
                                               const float* __restrict__ ie,
                                               half_t* __restrict__ x0h) {
    __shared__ int lcnt[NB];
    __shared__ int gbase[NB];
    int tid = threadIdx.x;
    if (blockIdx.x >= BGRID) {
        // ---- dropout-init body ----
        int j = (blockIdx.x - BGRID) * BIN_T + tid;   // [0, XH)
        if (j >= XH) return;
        unsigned o0, o1, b0, b1;
        threefry2x32(0u, 42u, 0u, (unsigned)j, o0, o1);        b0 = o0 ^ o1;
        threefry2x32(0u, 42u, 0u, (unsigned)(j + XH), o0, o1); b1 = o0 ^ o1;
        x0h[j]      = (half_t)dropout_val(ue, ie, j, b0);
        x0h[j + XH] = (half_t)dropout_val(ue, ie, j + XH, b1);
        return;
    }
    // ---- bin body ----
    for (int i = tid; i < NB; i += BIN_T) lcnt[i] = 0;
    __syncthreads();
    int base = blockIdx.x * BIN_CHUNK;
    int lp[BIN_U];          // (bucket<<13) | loff, or -1 for tail
    int2 rec[BIN_U];
    #pragma unroll
    for (int u = 0; u < BIN_U; ++u) {
        int idx = base + u * BIN_T + tid;
        if (idx < E) {
            int row = rows[idx];
            int col = cols[idx];
            float v = vals[idx];
            unsigned q = min(__float2int_rn(v * 65536.f), 16383);
            int b = row >> 10;
            int loff = atomicAdd(&lcnt[b], 1);
            lp[u] = (b << 13) | loff;               // loff < 4096 < 8192
            rec[u] = make_int2((int)((q << 18) | (unsigned)col), row);
        } else {
            lp[u] = -1;
        }
    }
    __syncthreads();
    for (int i = tid; i < NB; i += BIN_T)
        gbase[i] = atomicAdd(&pcnt[i * 16], lcnt[i]);   // 64B-padded counters
    __syncthreads();
    #pragma unroll
    for (int u = 0; u < BIN_U; ++u) {
        if (lp[u] >= 0) {
            int b = lp[u] >> 13;
            int pos = gbase[b] + (lp[u] & 8191);
            if (pos < BPC) stg[(size_t)b * BPC + pos] = rec[u];
        }
    }
}

// One block per bucket. Wave 0 computes this bucket's global base (redundant
// 147-prefix, replaces k_bscan). Then: LDS hist of 1024 rows, block scan,
// write rp, scatter records into the bucket's dense [bb, bb+tot) ev region.
__global__ void __launch_bounds__(1024) k_bsort(const int2* __restrict__ stg,
                                                const int* __restrict__ pcnt,
                                                int* __restrict__ rp,
                                                unsigned* __restrict__ ev) {
    __shared__ int cnt[1024];
    __shared__ int wsum[16];
    __shared__ int sbb;
    int b = blockIdx.x;
    int t = threadIdx.x;
    cnt[t] = 0;
    if (t < 64) {
        // exclusive prefix over buckets < b (one wave, <=3 values/lane)
        int a = 0;
        for (int i = t; i < b; i += 64) a += pcnt[i * 16];
        #pragma unroll
        for (int d = 1; d < 64; d <<= 1) a += __shfl_xor(a, d);
        if (t == 0) sbb = a;
    }
    if (b == 0 && t == 0) rp[NN] = E;    // sentinel
    __syncthreads();
    int tot = min(pcnt[b * 16], BPC);
    int bb = sbb;
    const int2* s = stg + (size_t)b * BPC;
    for (int i = t; i < tot; i += 1024)
        atomicAdd(&cnt[s[i].y & 1023], 1);
    __syncthreads();
    // Block-wide exclusive scan of cnt[1024].
    int v = cnt[t];
    int lane = t & 63, w = t >> 6;
    int x = v;
    #pragma unroll
    for (int d = 1; d < 64; d <<= 1) {
        int y = __shfl_up(x, d);
        if (lane >= d) x += y;
    }
    if (lane == 63) wsum[w] = x;
    __syncthreads();
    if (w == 0 && lane < 16) {
        int sv = wsum[lane];
        #pragma unroll
        for (int d = 1; d < 16; d <<= 1) {
            int y = __shfl_up(sv, d);
            if (lane >= d) sv += y;
        }
        wsum[lane] = sv;
    }
    __syncthreads();
    int excl = ((w > 0) ? wsum[w - 1] : 0) + x - v;
    int row = (b << 10) + t;
    if (row < NN) rp[row] = bb + excl;
    __syncthreads();
    cnt[t] = bb + excl;               // becomes the scatter cursor
    __syncthreads();
    for (int i = t; i < tot; i += 1024) {
        int2 r = s[i];
        int pos = atomicAdd(&cnt[r.y & 1023], 1);
        ev[pos] = (unsigned)r.x;
    }
}

// Pull SpMM over exact CSR, fp16 x. Wave = 8 rows; 8-lane group owns a row
// (lane l holds dims [8l,8l+8), 16B). Per 8-edge batch: next batch's ev codes
// prefetched first, then 8 shfl broadcasts, then 8 INDEPENDENT half8 gathers
// (8 outstanding 16B loads per lane), then the fma block.
// Padded edges (idx>=cnt) have code 0 -> v=0, gather x[0] (L1-hot), harmless.
// MODE 0: yh = A*xh (fp16 out). MODE 1: out_f32 = (x0h + y1h + xh + A*xh)*0.25.
template <int MODE>
__global__ void __launch_bounds__(256) k_spmm(const int* __restrict__ rp,
                                              const unsigned* __restrict__ ev,
                                              const half_t* __restrict__ xh,
                                              half_t* __restrict__ yh,
                                              const half_t* __restrict__ x0h,
                                              const half_t* __restrict__ y1h,
                                              float* __restrict__ out) {
    int wid  = threadIdx.x >> 6;             // wave in block: 0..3
    int lane = threadIdx.x & 63;
    int g    = lane >> 3;                    // group (row slot) 0..7
    int l    = lane & 7;                     // lane in group: dims [8l, 8l+8)
    int row  = blockIdx.x * 32 + wid * 8 + g;
    if (row >= NN) return;
    const float inv = 1.0f / 65536.0f;
    int s0  = rp[row];
    int cnt = rp[row + 1] - s0;
    float acc[8] = {0.f, 0.f, 0.f, 0.f, 0.f, 0.f, 0.f, 0.f};
    int gl = g << 3;                         // group's base lane
    int pc = (l < cnt) ? (int)ev[s0 + l] : 0;
    for (int base = 0; base < cnt; base += 8) {
        int nidx = base + 8 + l;
        int pcn = (nidx < cnt) ? (int)ev[s0 + nidx] : 0;   // prefetch next batch
        int pj[8];
        #pragma unroll
        for (int j = 0; j < 8; ++j) pj[j] = __shfl(pc, gl | j);
        half8 xv[8];
        #pragma unroll
        for (int j = 0; j < 8; ++j)
            xv[j] = *(const half8*)(xh + (pj[j] & 0x3FFFF) * 64 + l * 8);  // 16B
        #pragma unroll
        for (int j = 0; j < 8; ++j) {
            float vj = (float)((unsigned)pj[j] >> 18) * inv;
            #pragma unroll
            for (int k = 0; k < 8; ++k)
                acc[k] = fmaf(vj, (float)xv[j][k], acc[k]);
        }
        pc = pcn;
    }
    int o = row * 64 + l * 8;
    if (MODE == 0) {
        half8 st;
        #pragma unroll
        for (int k = 0; k < 8; ++k) st[k] = (half_t)acc[k];
        *(half8*)(yh + o) = st;
    } else {
        const half8 a0 = *(const half8*)(x0h + o);   // X0 (fp16)
        const half8 a1 = *(const half8*)(y1h + o);   // Y1 (fp16)
        const half8 a2 = *(const half8*)(xh + o);    // Y2 (linear read)
        float r[8];
        #pragma unroll
        for (int k = 0; k < 8; ++k)
            r[k] = ((float)a0[k] + (float)a1[k] + (float)a2[k] + acc[k]) * 0.25f;
        *(float4*)(out + o)     = make_float4(r[0], r[1], r[2], r[3]);
        *(float4*)(out + o + 4) = make_float4(r[4], r[5], r[6], r[7]);
    }
}

extern "C" void kernel_launch(void* const* d_in, const int* in_sizes, int n_in,
                              void* d_out, int out_size, void* d_ws, size_t ws_size,
                              hipStream_t stream) {
    const float* ue   = (const float*)d_in[0];
    const float* ie   = (const float*)d_in[1];
    const int*   rows = (const int*)d_in[2];
    const int*   cols = (const int*)d_in[3];
    const float* vals = (const float*)d_in[4];
    float* out = (float*)d_out;

    // Workspace: X0h [XN fp16 = 19.2MB] | Y1h [19.2MB] | Y2h [19.2MB]
    //   (stg aliases Y1h..Y2h: NB*BPC*8B = 28.2MB < 38.4MB, dead before spmm
    //    layer 1 writes Y1h) | ev [E*4 = 9.6MB] | rp [NN+1] | pcnt [NB*16].
    //   Total ~68 MB.
    half_t*   X0h   = (half_t*)d_ws;
    half_t*   Y1h   = X0h + XN;
    half_t*   Y2h   = Y1h + XN;
    int2*     stg   = (int2*)Y1h;
    unsigned* ev    = (unsigned*)(Y2h + XN);
    int*      rp    = (int*)(ev + E);
    int*      pcnt  = rp + NN + 4;

    (void)hipMemsetAsync(pcnt, 0, NB * 16 * sizeof(int), stream);
    k_pre<<<BGRID + DGRID, BIN_T, 0, stream>>>(rows, cols, vals, stg, pcnt,
                                               ue, ie, X0h);
    k_bsort<<<NB, 1024, 0, stream>>>(stg, pcnt, rp, ev);

    int sgrid = (NN + 31) / 32;   // 32 rows per block (4 waves x 8 rows)
    k_spmm<0><<<sgrid, 256, 0, stream>>>(rp, ev, X0h, Y1h, nullptr, nullptr, nullptr); // Y1=A*X0
    k_spmm<0><<<sgrid, 256, 0, stream>>>(rp, ev, Y1h, Y2h, nullptr, nullptr, nullptr); // Y2=A*Y1
    k_spmm<1><<<sgrid, 256, 0, stream>>>(rp, ev, Y2h, nullptr, X0h, Y1h, out);         // combine
}